// Round 11
// baseline (173.082 us; speedup 1.0000x reference)
//
#include <hip/hip_runtime.h>

typedef _Float16 f16;
typedef _Float16 f16x8 __attribute__((ext_vector_type(8)));
typedef float f32x4 __attribute__((ext_vector_type(4)));

// Async global->LDS, 16B per lane: lane i's 16B lands at base + i*16.
__device__ __forceinline__ void g2l16(const void* g, void* l) {
    __builtin_amdgcn_global_load_lds(
        (const __attribute__((address_space(1))) void*)g,
        (__attribute__((address_space(3))) void*)l, 16, 0, 0);
}

// Counted vmcnt wait (literal required in asm string).
template <int N> __device__ __forceinline__ void wait_vmcnt();
template <> __device__ __forceinline__ void wait_vmcnt<0>()  { asm volatile("s_waitcnt vmcnt(0)"  ::: "memory"); }
template <> __device__ __forceinline__ void wait_vmcnt<4>()  { asm volatile("s_waitcnt vmcnt(4)"  ::: "memory"); }
template <> __device__ __forceinline__ void wait_vmcnt<6>()  { asm volatile("s_waitcnt vmcnt(6)"  ::: "memory"); }
template <> __device__ __forceinline__ void wait_vmcnt<8>()  { asm volatile("s_waitcnt vmcnt(8)"  ::: "memory"); }
template <> __device__ __forceinline__ void wait_vmcnt<12>() { asm volatile("s_waitcnt vmcnt(12)" ::: "memory"); }

template <int V> struct ic { static constexpr int value = V; };

__device__ __forceinline__ float soft1(float a, float thr, float w, float s) {
    return copysignf(fmaxf(a - thr, 0.0f), w) * s;
}

__device__ __forceinline__ float thr4(float a0, float a1, float a2, float a3) {
    float lo01 = fminf(a0, a1), hi01 = fmaxf(a0, a1);
    float lo23 = fminf(a2, a3), hi23 = fmaxf(a2, a3);
    return fminf(fmaxf(lo01, lo23), fminf(hi01, hi23));
}

// One launch: [0, nCastB)        -> cast x fp32 -> f16 (cheaper than any
//             in-GEMM fusion: rounds 3/4 measured +32us for fused variants)
//             [nCastB, +nSpInB)  -> sparsify w_in   (2:4 along R), out winT  [R][D]
//             [.., +nSpOutB)     -> sparsify w_out^T (2:4 along D), out woutT [D][R]
__global__ __launch_bounds__(256) void prep_kernel(
    const float* __restrict__ x, f16* __restrict__ xh, int n8,
    const float* __restrict__ Wi, f16* __restrict__ winT, const float* __restrict__ sci,
    const float* __restrict__ Wo, f16* __restrict__ woutT, const float* __restrict__ sco,
    int D, int R, int nCastB, int nSpInB)
{
    int b = blockIdx.x;
    int tid = threadIdx.x;
    if (b < nCastB) {
        int i = b * 256 + tid;
        if (i < n8) {
            float4 a = reinterpret_cast<const float4*>(x)[2 * i];
            float4 c = reinterpret_cast<const float4*>(x)[2 * i + 1];
            f16x8 o = {(f16)a.x, (f16)a.y, (f16)a.z, (f16)a.w,
                       (f16)c.x, (f16)c.y, (f16)c.z, (f16)c.w};
            reinterpret_cast<f16x8*>(xh)[i] = o;
        }
    } else if (b < nCastB + nSpInB) {
        int t = (b - nCastB) * 256 + tid;   // t = rg*D + d (coalesced writes)
        int RG = R >> 2;
        if (t >= RG * D) return;
        int rg = t / D, d = t - rg * D;
        float s = *sci;
        float4 w = *reinterpret_cast<const float4*>(Wi + (size_t)d * R + rg * 4);
        float a0 = fabsf(w.x), a1 = fabsf(w.y), a2 = fabsf(w.z), a3 = fabsf(w.w);
        float thr = thr4(a0, a1, a2, a3);
        size_t base = (size_t)(rg * 4) * D + d;
        winT[base]                 = (f16)soft1(a0, thr, w.x, s);
        winT[base + D]             = (f16)soft1(a1, thr, w.y, s);
        winT[base + 2 * (size_t)D] = (f16)soft1(a2, thr, w.z, s);
        winT[base + 3 * (size_t)D] = (f16)soft1(a3, thr, w.w, s);
    } else {
        int t = (b - nCastB - nSpInB) * 256 + tid;  // t = dg*R + r
        if (t >= (D >> 2) * R) return;
        int dg = t / R, r = t - dg * R;
        float s = *sco;
        size_t i0 = (size_t)(dg * 4) * R + r;
        float w0 = Wo[i0], w1 = Wo[i0 + R], w2 = Wo[i0 + 2 * (size_t)R], w3 = Wo[i0 + 3 * (size_t)R];
        float a0 = fabsf(w0), a1 = fabsf(w1), a2 = fabsf(w2), a3 = fabsf(w3);
        float thr = thr4(a0, a1, a2, a3);
        woutT[i0]                 = (f16)soft1(a0, thr, w0, s);
        woutT[i0 + R]             = (f16)soft1(a1, thr, w1, s);
        woutT[i0 + 2 * (size_t)R] = (f16)soft1(a2, thr, w2, s);
        woutT[i0 + 3 * (size_t)R] = (f16)soft1(a3, thr, w3, s);
    }
}

// C[M][N] = A[M][K] f16 @ Bt[N][K]^T f16, fp32 accum.
// Round-10 proven structure (169.3us): counted-vmcnt DEPTH-buffered
// 2-barrier K-step, TBK=64 both GEMMs, g2l16 both operands, XCD-bijective
// block swizzle, chunk-XOR bank swizzle (both sides, rule 21).
// Round-11 change: ks=0 MFMA cluster moved BEFORE lgkmcnt(0)/barrier2 —
// reads for both K-subtiles issue first, compiler inserts lgkmcnt(6/8)
// before the ks0 cluster (compiler-tracked loads, not inline-asm ds_read,
// so rule-18's hoist hazard doesn't apply; sched_barrier(0) fences pin the
// clusters), so ks0's MFMAs overlap ks1's read completion. barrier2/STAGE
// delayed ~40-77cy, absorbed by the >=1-step prefetch slack.
// (1-barrier variant regressed +5us in round 9 — keep 2 barriers.)
template <int TBM, int TBN, int TBK, int DEPTH, typename OT, bool BIAS>
__global__ __launch_bounds__(256) void gemm_bt(
    const f16* __restrict__ A, const f16* __restrict__ Bt, OT* __restrict__ C,
    const float* __restrict__ bias, int M, int N, int K)
{
    constexpr int KS = TBK / 32;   // 32-deep K-subtiles per LDS tile
    constexpr int MI = TBM / 32;   // A-fragments per wave per K-subtile
    constexpr int NF = TBN / 32;   // B-fragments per wave per K-subtile
    constexpr int HM = TBM / 2;    // per-wave M span
    constexpr int HN = TBN / 2;    // per-wave N span
    constexpr int RPO = 512 / TBK;            // rows covered per g2l16 wave-op
    constexpr int L  = (TBM + TBN) / 64 * KS; // g2l16 per thread per tile
    __shared__ f16 As[DEPTH][TBM * TBK];
    __shared__ f16 Bs[DEPTH][TBN * TBK];

    const int tid  = threadIdx.x;
    const int lane = tid & 63;
    const int w    = tid >> 6;
    const int wm   = w & 1;
    const int wn   = w >> 1;
    const int l16  = lane & 15;
    const int quad = lane >> 4;

    // XCD swizzle: HW round-robins consecutive dispatches across 8 XCDs.
    const int nbx = N / TBN;
    const int nb  = gridDim.x;
    int d = blockIdx.x;
    int wgid = ((nb & 7) == 0) ? ((d & 7) * (nb >> 3) + (d >> 3)) : d;
    int by = wgid / nbx;
    int bx = wgid - by * nbx;
    const int bm = by * TBM;
    const int bn = bx * TBN;

    // Staging: one wave-op = 64 lanes x 16B = RPO rows x TBK halves.
    // Chunk-XOR source swizzle (LDS dest linear, rule 21).
    constexpr int CPR = TBK / 8;              // 16B chunks per row
    const int srow = lane / CPR;
    const int scol = ((lane % CPR) ^ (srow % CPR)) * 8;
    const f16* gA = A  + (size_t)(bm + w * (TBM / 4) + srow) * K + scol;
    const f16* gB = Bt + (size_t)(bn + w * (TBN / 4) + srow) * K + scol;

    f32x4 acc[MI][NF] = {};

    auto STAGE = [&](int buf, int t) {
        const size_t k0 = (size_t)t * TBK;
        f16* lA = &As[buf][(w * (TBM / 4)) * TBK];
        f16* lB = &Bs[buf][(w * (TBN / 4)) * TBK];
#pragma unroll
        for (int i = 0; i < (TBM / 4) / RPO; ++i)
            g2l16(gA + k0 + i * RPO * (size_t)K, lA + i * RPO * TBK);
#pragma unroll
        for (int i = 0; i < (TBN / 4) / RPO; ++i)
            g2l16(gB + k0 + i * RPO * (size_t)K, lB + i * RPO * TBK);
    };

    // Fragment read: chunk index XOR'd with row % CPR (= l16 % CPR, since
    // all row bases are multiples of 16). ks=0 reads issue FIRST (the ks0
    // MFMA cluster waits only on them).
    auto LOADFRAG = [&](int buf, f16x8* af, f16x8* bf) {
        const int xc = (l16 % CPR);
#pragma unroll
        for (int ks = 0; ks < KS; ++ks) {
#pragma unroll
            for (int m = 0; m < MI; ++m) {
                int row = wm * HM + m * 16 + l16;
                int ch  = ((ks * 4 + quad) ^ xc) * 8;
                af[m * KS + ks] = *reinterpret_cast<const f16x8*>(&As[buf][row * TBK + ch]);
            }
#pragma unroll
            for (int n = 0; n < NF; ++n) {
                int row = wn * HN + n * 16 + l16;
                int ch  = ((ks * 4 + quad) ^ xc) * 8;
                bf[n * KS + ks] = *reinterpret_cast<const f16x8*>(&Bs[buf][row * TBK + ch]);
            }
        }
    };

    // MFMA over ks in [KS0, KS1) — static unroll only (rule 20).
    auto MFMA_PART = [&](f16x8* af, f16x8* bf, auto KS0, auto KS1) {
#pragma unroll
        for (int ks = decltype(KS0)::value; ks < decltype(KS1)::value; ++ks)
#pragma unroll
            for (int m = 0; m < MI; ++m)
#pragma unroll
                for (int n = 0; n < NF; ++n)
                    acc[m][n] = __builtin_amdgcn_mfma_f32_16x16x32_f16(
                        af[m * KS + ks], bf[n * KS + ks], acc[m][n], 0, 0, 0);
    };

    const int nk = K / TBK;   // G1: 32, G2: 8
#pragma unroll
    for (int p = 0; p < DEPTH; ++p)
        STAGE(p, p);
    int buf = 0;
    for (int t = 0; t < nk - DEPTH; ++t) {
        wait_vmcnt<(DEPTH - 1) * L>();      // tile t landed; rest in flight
        __builtin_amdgcn_s_barrier();
        __builtin_amdgcn_sched_barrier(0);
        f16x8 af[MI * KS], bf[NF * KS];
        LOADFRAG(buf, af, bf);              // issue all 2*ks read groups
        __builtin_amdgcn_sched_barrier(0);
        MFMA_PART(af, bf, ic<0>{}, ic<1>{});   // ks0: overlaps ks1 read drain
        __builtin_amdgcn_sched_barrier(0);
        asm volatile("s_waitcnt lgkmcnt(0)" ::: "memory");
        __builtin_amdgcn_sched_barrier(0);  // my reads done before release
        __builtin_amdgcn_s_barrier();       // buf released by all waves
        STAGE(buf, t + DEPTH);              // async overwrite; overlaps MFMA
        __builtin_amdgcn_sched_barrier(0);
        MFMA_PART(af, bf, ic<1>{}, ic<KS>{});
        buf = (buf + 1 == DEPTH) ? 0 : buf + 1;
    }
    // tail: last DEPTH tiles, nothing left to stage; waits step down by L.
    auto TAILSTEP = [&](auto VM, int b) {
        wait_vmcnt<decltype(VM)::value>();
        __builtin_amdgcn_s_barrier();
        __builtin_amdgcn_sched_barrier(0);
        f16x8 af[MI * KS], bf[NF * KS];
        LOADFRAG(b, af, bf);
        MFMA_PART(af, bf, ic<0>{}, ic<KS>{});
    };
    if constexpr (DEPTH == 3) {
        TAILSTEP(ic<2 * L>{}, buf);
        buf = (buf + 1 == DEPTH) ? 0 : buf + 1;
    }
    TAILSTEP(ic<L>{}, buf);
    buf = (buf + 1 == DEPTH) ? 0 : buf + 1;
    TAILSTEP(ic<0>{}, buf);

    // epilogue: C/D layout row = quad*4 + r, col = lane&15
#pragma unroll
    for (int m = 0; m < MI; ++m) {
        int row_base = bm + wm * HM + m * 16 + quad * 4;
#pragma unroll
        for (int n = 0; n < NF; ++n) {
            int col = bn + wn * HN + n * 16 + l16;
            float b = BIAS ? bias[col] : 0.0f;
#pragma unroll
            for (int r = 0; r < 4; ++r) {
                float v = acc[m][n][r];
                size_t idx = (size_t)(row_base + r) * N + col;
                if constexpr (BIAS) C[idx] = (OT)(v + b);
                else                C[idx] = (OT)v;
            }
        }
    }
}

extern "C" void kernel_launch(void* const* d_in, const int* in_sizes, int n_in,
                              void* d_out, int out_size, void* d_ws, size_t ws_size,
                              hipStream_t stream)
{
    const float* x      = (const float*)d_in[0];
    const float* w_in   = (const float*)d_in[1];
    const float* w_out  = (const float*)d_in[2];
    const float* bias   = (const float*)d_in[3];
    const float* sc_in  = (const float*)d_in[4];
    const float* sc_out = (const float*)d_in[5];

    const int D = in_sizes[3];            // 2048
    const int R = in_sizes[1] / D;        // 512
    const int M = in_sizes[0] / D;        // 8192 (B*S)

    f16* winT  = (f16*)d_ws;                      // [R][D]
    f16* woutT = winT + (size_t)R * D;            // [D][R]
    f16* h     = woutT + (size_t)D * R;           // [M][R]
    f16* xh    = h + (size_t)M * R;               // [M][D]
    float* out = (float*)d_out;

    const int n8 = M * D / 8;
    const int nCastB  = (n8 + 255) / 256;
    const int nSpInB  = ((R / 4) * D + 255) / 256;
    const int nSpOutB = ((D / 4) * R + 255) / 256;
    prep_kernel<<<nCastB + nSpInB + nSpOutB, 256, 0, stream>>>(
        x, xh, n8, w_in, winT, sc_in, w_out, woutT, sc_out, D, R, nCastB, nSpInB);

    // GEMM1: M=8192, N=512, K=2048. 64x128 tile, TBK=64, DEPTH=3 (72KB LDS,
    // 2 blocks/CU), 512 blocks.
    gemm_bt<64, 128, 64, 3, f16, false><<<(R / 128) * (M / 64), 256, 0, stream>>>(
        xh, winT, h, nullptr, M, R, D);
    // GEMM2: M=8192, N=2048, K=512. 128x128 tile, TBK=64 (8 K-steps x 32
    // MFMA), DEPTH=2 (64KB LDS, 2 blocks/CU), 1024 blocks.
    gemm_bt<128, 128, 64, 2, float, true><<<(D / 128) * (M / 128), 256, 0, stream>>>(
        h, woutT, out, bias, M, D, R);
}

// Round 12
// 167.976 us; speedup vs baseline: 1.0304x; 1.0304x over previous
//
#include <hip/hip_runtime.h>

typedef _Float16 f16;
typedef _Float16 f16x8 __attribute__((ext_vector_type(8)));
typedef float f32x4 __attribute__((ext_vector_type(4)));

// Async global->LDS, 16B per lane: lane i's 16B lands at base + i*16.
__device__ __forceinline__ void g2l16(const void* g, void* l) {
    __builtin_amdgcn_global_load_lds(
        (const __attribute__((address_space(1))) void*)g,
        (__attribute__((address_space(3))) void*)l, 16, 0, 0);
}

// Counted vmcnt wait (literal required in asm string).
template <int N> __device__ __forceinline__ void wait_vmcnt();
template <> __device__ __forceinline__ void wait_vmcnt<0>()  { asm volatile("s_waitcnt vmcnt(0)"  ::: "memory"); }
template <> __device__ __forceinline__ void wait_vmcnt<4>()  { asm volatile("s_waitcnt vmcnt(4)"  ::: "memory"); }
template <> __device__ __forceinline__ void wait_vmcnt<6>()  { asm volatile("s_waitcnt vmcnt(6)"  ::: "memory"); }
template <> __device__ __forceinline__ void wait_vmcnt<8>()  { asm volatile("s_waitcnt vmcnt(8)"  ::: "memory"); }
template <> __device__ __forceinline__ void wait_vmcnt<12>() { asm volatile("s_waitcnt vmcnt(12)" ::: "memory"); }

template <int V> struct ic { static constexpr int value = V; };

__device__ __forceinline__ float soft1(float a, float thr, float w, float s) {
    return copysignf(fmaxf(a - thr, 0.0f), w) * s;
}

__device__ __forceinline__ float thr4(float a0, float a1, float a2, float a3) {
    float lo01 = fminf(a0, a1), hi01 = fmaxf(a0, a1);
    float lo23 = fminf(a2, a3), hi23 = fmaxf(a2, a3);
    return fminf(fmaxf(lo01, lo23), fminf(hi01, hi23));
}

// One launch: [0, nCastB)        -> cast x fp32 -> f16 (cheaper than any
//             in-GEMM fusion: rounds 3/4 measured +32us for fused variants)
//             [nCastB, +nSpInB)  -> sparsify w_in   (2:4 along R), out winT  [R][D]
//             [.., +nSpOutB)     -> sparsify w_out^T (2:4 along D), out woutT [D][R]
__global__ __launch_bounds__(256) void prep_kernel(
    const float* __restrict__ x, f16* __restrict__ xh, int n8,
    const float* __restrict__ Wi, f16* __restrict__ winT, const float* __restrict__ sci,
    const float* __restrict__ Wo, f16* __restrict__ woutT, const float* __restrict__ sco,
    int D, int R, int nCastB, int nSpInB)
{
    int b = blockIdx.x;
    int tid = threadIdx.x;
    if (b < nCastB) {
        int i = b * 256 + tid;
        if (i < n8) {
            float4 a = reinterpret_cast<const float4*>(x)[2 * i];
            float4 c = reinterpret_cast<const float4*>(x)[2 * i + 1];
            f16x8 o = {(f16)a.x, (f16)a.y, (f16)a.z, (f16)a.w,
                       (f16)c.x, (f16)c.y, (f16)c.z, (f16)c.w};
            reinterpret_cast<f16x8*>(xh)[i] = o;
        }
    } else if (b < nCastB + nSpInB) {
        int t = (b - nCastB) * 256 + tid;   // t = rg*D + d (coalesced writes)
        int RG = R >> 2;
        if (t >= RG * D) return;
        int rg = t / D, d = t - rg * D;
        float s = *sci;
        float4 w = *reinterpret_cast<const float4*>(Wi + (size_t)d * R + rg * 4);
        float a0 = fabsf(w.x), a1 = fabsf(w.y), a2 = fabsf(w.z), a3 = fabsf(w.w);
        float thr = thr4(a0, a1, a2, a3);
        size_t base = (size_t)(rg * 4) * D + d;
        winT[base]                 = (f16)soft1(a0, thr, w.x, s);
        winT[base + D]             = (f16)soft1(a1, thr, w.y, s);
        winT[base + 2 * (size_t)D] = (f16)soft1(a2, thr, w.z, s);
        winT[base + 3 * (size_t)D] = (f16)soft1(a3, thr, w.w, s);
    } else {
        int t = (b - nCastB - nSpInB) * 256 + tid;  // t = dg*R + r
        if (t >= (D >> 2) * R) return;
        int dg = t / R, r = t - dg * R;
        float s = *sco;
        size_t i0 = (size_t)(dg * 4) * R + r;
        float w0 = Wo[i0], w1 = Wo[i0 + R], w2 = Wo[i0 + 2 * (size_t)R], w3 = Wo[i0 + 3 * (size_t)R];
        float a0 = fabsf(w0), a1 = fabsf(w1), a2 = fabsf(w2), a3 = fabsf(w3);
        float thr = thr4(a0, a1, a2, a3);
        woutT[i0]                 = (f16)soft1(a0, thr, w0, s);
        woutT[i0 + R]             = (f16)soft1(a1, thr, w1, s);
        woutT[i0 + 2 * (size_t)R] = (f16)soft1(a2, thr, w2, s);
        woutT[i0 + 3 * (size_t)R] = (f16)soft1(a3, thr, w3, s);
    }
}

// C[M][N] = A[M][K] f16 @ Bt[N][K]^T f16, fp32 accum.
// BEST CONFIG (round 10, 169.3us): counted-vmcnt DEPTH-buffered 2-barrier
// K-step, TBK=64 both GEMMs, g2l16 both operands, XCD-bijective block
// swizzle, chunk-XOR bank swizzle (both sides, rule 21).
// Structure ledger (do not re-try):
//   r9  1-barrier K-step: +5us (2nd barrier enables wave skew: one wave's
//       STAGE overlaps another's MFMA — it is load-bearing).
//   r11 ks0-MFMA before barrier2: +3.8us (delays barrier2/STAGE on every
//       wave; early release + early STAGE issue beats intra-wave overlap).
//   r8  depth-3 vs depth-2 in-flight: null. r6 bank swizzle alone: null
//       (kept because free and enables TBK=64 read pattern).
//   r3/r4 cast fusion into G1 (LDS-side and reg-side): +24/+21us.
template <int TBM, int TBN, int TBK, int DEPTH, typename OT, bool BIAS>
__global__ __launch_bounds__(256) void gemm_bt(
    const f16* __restrict__ A, const f16* __restrict__ Bt, OT* __restrict__ C,
    const float* __restrict__ bias, int M, int N, int K)
{
    constexpr int KS = TBK / 32;   // 32-deep K-subtiles per LDS tile
    constexpr int MI = TBM / 32;   // A-fragments per wave per K-subtile
    constexpr int NF = TBN / 32;   // B-fragments per wave per K-subtile
    constexpr int HM = TBM / 2;    // per-wave M span
    constexpr int HN = TBN / 2;    // per-wave N span
    constexpr int RPO = 512 / TBK;            // rows covered per g2l16 wave-op
    constexpr int L  = (TBM + TBN) / 64 * KS; // g2l16 per thread per tile
    __shared__ f16 As[DEPTH][TBM * TBK];
    __shared__ f16 Bs[DEPTH][TBN * TBK];

    const int tid  = threadIdx.x;
    const int lane = tid & 63;
    const int w    = tid >> 6;
    const int wm   = w & 1;
    const int wn   = w >> 1;
    const int l16  = lane & 15;
    const int quad = lane >> 4;

    // XCD swizzle: HW round-robins consecutive dispatches across 8 XCDs.
    const int nbx = N / TBN;
    const int nb  = gridDim.x;
    int d = blockIdx.x;
    int wgid = ((nb & 7) == 0) ? ((d & 7) * (nb >> 3) + (d >> 3)) : d;
    int by = wgid / nbx;
    int bx = wgid - by * nbx;
    const int bm = by * TBM;
    const int bn = bx * TBN;

    // Staging: one wave-op = 64 lanes x 16B = RPO rows x TBK halves.
    // Chunk-XOR source swizzle (LDS dest linear, rule 21).
    constexpr int CPR = TBK / 8;              // 16B chunks per row
    const int srow = lane / CPR;
    const int scol = ((lane % CPR) ^ (srow % CPR)) * 8;
    const f16* gA = A  + (size_t)(bm + w * (TBM / 4) + srow) * K + scol;
    const f16* gB = Bt + (size_t)(bn + w * (TBN / 4) + srow) * K + scol;

    f32x4 acc[MI][NF] = {};

    auto STAGE = [&](int buf, int t) {
        const size_t k0 = (size_t)t * TBK;
        f16* lA = &As[buf][(w * (TBM / 4)) * TBK];
        f16* lB = &Bs[buf][(w * (TBN / 4)) * TBK];
#pragma unroll
        for (int i = 0; i < (TBM / 4) / RPO; ++i)
            g2l16(gA + k0 + i * RPO * (size_t)K, lA + i * RPO * TBK);
#pragma unroll
        for (int i = 0; i < (TBN / 4) / RPO; ++i)
            g2l16(gB + k0 + i * RPO * (size_t)K, lB + i * RPO * TBK);
    };

    // Fragment read: chunk index XOR'd with row % CPR (= l16 % CPR, since
    // all row bases are multiples of 16).
    auto LOADFRAG = [&](int buf, f16x8* af, f16x8* bf) {
        const int xc = (l16 % CPR);
#pragma unroll
        for (int ks = 0; ks < KS; ++ks) {
#pragma unroll
            for (int m = 0; m < MI; ++m) {
                int row = wm * HM + m * 16 + l16;
                int ch  = ((ks * 4 + quad) ^ xc) * 8;
                af[m * KS + ks] = *reinterpret_cast<const f16x8*>(&As[buf][row * TBK + ch]);
            }
#pragma unroll
            for (int n = 0; n < NF; ++n) {
                int row = wn * HN + n * 16 + l16;
                int ch  = ((ks * 4 + quad) ^ xc) * 8;
                bf[n * KS + ks] = *reinterpret_cast<const f16x8*>(&Bs[buf][row * TBK + ch]);
            }
        }
    };

    auto MFMA_ALL = [&](f16x8* af, f16x8* bf) {
#pragma unroll
        for (int ks = 0; ks < KS; ++ks)
#pragma unroll
            for (int m = 0; m < MI; ++m)
#pragma unroll
                for (int n = 0; n < NF; ++n)
                    acc[m][n] = __builtin_amdgcn_mfma_f32_16x16x32_f16(
                        af[m * KS + ks], bf[n * KS + ks], acc[m][n], 0, 0, 0);
    };

    const int nk = K / TBK;   // G1: 32, G2: 8
#pragma unroll
    for (int p = 0; p < DEPTH; ++p)
        STAGE(p, p);
    int buf = 0;
    for (int t = 0; t < nk - DEPTH; ++t) {
        wait_vmcnt<(DEPTH - 1) * L>();      // tile t landed; rest in flight
        __builtin_amdgcn_s_barrier();
        __builtin_amdgcn_sched_barrier(0);
        f16x8 af[MI * KS], bf[NF * KS];
        LOADFRAG(buf, af, bf);
        asm volatile("s_waitcnt lgkmcnt(0)" ::: "memory");
        __builtin_amdgcn_sched_barrier(0);  // my reads done before release
        __builtin_amdgcn_s_barrier();       // buf released by all waves
        STAGE(buf, t + DEPTH);              // async overwrite; overlaps MFMA
        MFMA_ALL(af, bf);
        buf = (buf + 1 == DEPTH) ? 0 : buf + 1;
    }
    // tail: last DEPTH tiles, nothing left to stage; waits step down by L.
    auto TAILSTEP = [&](auto VM, int b) {
        wait_vmcnt<decltype(VM)::value>();
        __builtin_amdgcn_s_barrier();
        __builtin_amdgcn_sched_barrier(0);
        f16x8 af[MI * KS], bf[NF * KS];
        LOADFRAG(b, af, bf);
        MFMA_ALL(af, bf);
    };
    if constexpr (DEPTH == 3) {
        TAILSTEP(ic<2 * L>{}, buf);
        buf = (buf + 1 == DEPTH) ? 0 : buf + 1;
    }
    TAILSTEP(ic<L>{}, buf);
    buf = (buf + 1 == DEPTH) ? 0 : buf + 1;
    TAILSTEP(ic<0>{}, buf);

    // epilogue: C/D layout row = quad*4 + r, col = lane&15
#pragma unroll
    for (int m = 0; m < MI; ++m) {
        int row_base = bm + wm * HM + m * 16 + quad * 4;
#pragma unroll
        for (int n = 0; n < NF; ++n) {
            int col = bn + wn * HN + n * 16 + l16;
            float b = BIAS ? bias[col] : 0.0f;
#pragma unroll
            for (int r = 0; r < 4; ++r) {
                float v = acc[m][n][r];
                size_t idx = (size_t)(row_base + r) * N + col;
                if constexpr (BIAS) C[idx] = (OT)(v + b);
                else                C[idx] = (OT)v;
            }
        }
    }
}

extern "C" void kernel_launch(void* const* d_in, const int* in_sizes, int n_in,
                              void* d_out, int out_size, void* d_ws, size_t ws_size,
                              hipStream_t stream)
{
    const float* x      = (const float*)d_in[0];
    const float* w_in   = (const float*)d_in[1];
    const float* w_out  = (const float*)d_in[2];
    const float* bias   = (const float*)d_in[3];
    const float* sc_in  = (const float*)d_in[4];
    const float* sc_out = (const float*)d_in[5];

    const int D = in_sizes[3];            // 2048
    const int R = in_sizes[1] / D;        // 512
    const int M = in_sizes[0] / D;        // 8192 (B*S)

    f16* winT  = (f16*)d_ws;                      // [R][D]
    f16* woutT = winT + (size_t)R * D;            // [D][R]
    f16* h     = woutT + (size_t)D * R;           // [M][R]
    f16* xh    = h + (size_t)M * R;               // [M][D]
    float* out = (float*)d_out;

    const int n8 = M * D / 8;
    const int nCastB  = (n8 + 255) / 256;
    const int nSpInB  = ((R / 4) * D + 255) / 256;
    const int nSpOutB = ((D / 4) * R + 255) / 256;
    prep_kernel<<<nCastB + nSpInB + nSpOutB, 256, 0, stream>>>(
        x, xh, n8, w_in, winT, sc_in, w_out, woutT, sc_out, D, R, nCastB, nSpInB);

    // GEMM1: M=8192, N=512, K=2048. 64x128 tile, TBK=64, DEPTH=3 (72KB LDS,
    // 2 blocks/CU), 512 blocks.
    gemm_bt<64, 128, 64, 3, f16, false><<<(R / 128) * (M / 64), 256, 0, stream>>>(
        xh, winT, h, nullptr, M, R, D);
    // GEMM2: M=8192, N=2048, K=512. 128x128 tile, TBK=64 (8 K-steps x 32
    // MFMA), DEPTH=2 (64KB LDS, 2 blocks/CU), 1024 blocks.
    gemm_bt<128, 128, 64, 2, float, true><<<(D / 128) * (M / 128), 256, 0, stream>>>(
        h, woutT, out, bias, M, D, R);
}